// Round 1
// baseline (168.577 us; speedup 1.0000x reference)
//
#include <hip/hip_runtime.h>
#include <hip/hip_bf16.h>

// Problem: B=16, S=1024, IN=512, OUT=256.
// out = softmax((x@wq^T + bq)(x@wk^T + bk)^T / sqrt(512)) @ (x@wv^T + bv)
// RoPE cancels (same rotation on q and k) -> skipped.
// Pipeline: cvt(fp32->bf16) -> qkv_gemm (bf16 MFMA, writes q,k,v_t) -> flash attn.

typedef __attribute__((ext_vector_type(8))) short short8;
typedef __attribute__((ext_vector_type(4))) short short4v;
typedef __attribute__((ext_vector_type(4))) float f32x4;

#define GLL16(g, l)                                                            \
  __builtin_amdgcn_global_load_lds(                                            \
      (const __attribute__((address_space(1))) unsigned int*)(g),              \
      (__attribute__((address_space(3))) unsigned int*)(l), 16, 0, 0)

static __device__ __forceinline__ short f2bf(float f) {
  __hip_bfloat16 h = __float2bfloat16(f);
  return __builtin_bit_cast(short, h);
}

// ---------------- fp32 -> bf16 converts ----------------
__global__ void cvt_x(const float* __restrict__ src, short* __restrict__ dst, int n8) {
  int i = blockIdx.x * blockDim.x + threadIdx.x;
  int stride = gridDim.x * blockDim.x;
  for (; i < n8; i += stride) {
    const float4* sp = reinterpret_cast<const float4*>(src) + i * 2;
    float4 a = sp[0], b = sp[1];
    short8 o;
    o[0] = f2bf(a.x); o[1] = f2bf(a.y); o[2] = f2bf(a.z); o[3] = f2bf(a.w);
    o[4] = f2bf(b.x); o[5] = f2bf(b.y); o[6] = f2bf(b.z); o[7] = f2bf(b.w);
    *(reinterpret_cast<short8*>(dst) + i) = o;
  }
}

__global__ void cvt_w(const float* __restrict__ wq, const float* __restrict__ wk,
                      const float* __restrict__ wv, short* __restrict__ dst) {
  int i = blockIdx.x * blockDim.x + threadIdx.x;  // 0..49151 (49152 * 8 = 393216 elems)
  if (i >= 49152) return;
  const float* src;
  int off;
  if (i < 16384)      { src = wq; off = i; }
  else if (i < 32768) { src = wk; off = i - 16384; }
  else                { src = wv; off = i - 32768; }
  const float4* sp = reinterpret_cast<const float4*>(src) + off * 2;
  float4 a = sp[0], b = sp[1];
  short8 o;
  o[0] = f2bf(a.x); o[1] = f2bf(a.y); o[2] = f2bf(a.z); o[3] = f2bf(a.w);
  o[4] = f2bf(b.x); o[5] = f2bf(b.y); o[6] = f2bf(b.z); o[7] = f2bf(b.w);
  *(reinterpret_cast<short8*>(dst) + i) = o;
}

// ---------------- QKV GEMM ----------------
// C[16384 x 768] = xb[16384 x 512] @ wb[768 x 512]^T
// 128x128 tile, BK=64, 4 waves (2x2), each wave 64x64 = 4x4 frags of 16x16x32.
// LDS tiles A[128][64],B[128][64] bf16, 16B-chunk XOR swizzle (chunk ^= row&7),
// staged via global_load_lds with pre-swizzled global source.
// Epilogue: cols 0-255 -> q (scaled 1/sqrt(512), +bq), 256-511 -> k (+bk),
//           512-767 -> v_t[b][d][s] (+bv), all bf16.
__global__ __launch_bounds__(256) void qkv_gemm(
    const short* __restrict__ xb, const short* __restrict__ wb,
    const float* __restrict__ bq, const float* __restrict__ bk,
    const float* __restrict__ bv, short* __restrict__ qb,
    short* __restrict__ kb, short* __restrict__ vt) {
  __shared__ __align__(16) char smem[32768];
  const int bid = blockIdx.x;                 // 768 blocks
  const int swz = (bid & 7) * 96 + (bid >> 3);  // bijective XCD chunking (768 % 8 == 0)
  const int mt = swz / 6, nt = swz % 6;
  const int tid = threadIdx.x;
  const int w = tid >> 6, lane = tid & 63;
  const int g = lane >> 4, c = lane & 15;
  const int wm = w >> 1, wn = w & 1;

  f32x4 acc[4][4];
  const f32x4 fzero = {0.f, 0.f, 0.f, 0.f};
#pragma unroll
  for (int mi = 0; mi < 4; mi++)
#pragma unroll
    for (int ni = 0; ni < 4; ni++) acc[mi][ni] = fzero;

  for (int kk = 0; kk < 8; ++kk) {
    __syncthreads();
    // stage 32KB: waves 0-1 -> A (16 x 1KB), waves 2-3 -> B
#pragma unroll
    for (int i = 0; i < 8; i++) {
      int idx = w * 8 + i;                 // 0..31
      int r = (idx & 15) * 8 + (lane >> 3);  // row within tile
      int cc = lane & 7;                   // 16B chunk within 128B row
      const short* src;
      if (idx < 16)
        src = xb + (mt * 128 + r) * 512 + kk * 64 + ((cc ^ (r & 7)) * 8);
      else
        src = wb + (nt * 128 + r) * 512 + kk * 64 + ((cc ^ (r & 7)) * 8);
      GLL16(src, smem + idx * 1024);
    }
    asm volatile("s_waitcnt vmcnt(0)" ::: "memory");
    __syncthreads();
#pragma unroll
    for (int ks = 0; ks < 2; ++ks) {
      short8 af[4], bf[4];
#pragma unroll
      for (int mi = 0; mi < 4; mi++) {
        int row = wm * 64 + mi * 16 + c;
        af[mi] = *(const short8*)(smem + row * 128 + (((ks * 4 + g) ^ (row & 7)) * 16));
      }
#pragma unroll
      for (int ni = 0; ni < 4; ni++) {
        int row = wn * 64 + ni * 16 + c;
        bf[ni] = *(const short8*)(smem + 16384 + row * 128 + (((ks * 4 + g) ^ (row & 7)) * 16));
      }
#pragma unroll
      for (int mi = 0; mi < 4; mi++)
#pragma unroll
        for (int ni = 0; ni < 4; ni++)
          acc[mi][ni] = __builtin_amdgcn_mfma_f32_16x16x32_bf16(af[mi], bf[ni], acc[mi][ni], 0, 0, 0);
    }
  }

  // epilogue — C/D layout: col = lane&15, row = (lane>>4)*4 + reg
  const int colbase = nt * 128 + wn * 64;
  const int cls = colbase >> 8;  // 0=q 1=k 2=v (uniform per block-half)
  const int cw = colbase & 255;
  const int rowbase = mt * 128 + wm * 64;
  if (cls == 0) {
#pragma unroll
    for (int mi = 0; mi < 4; mi++)
#pragma unroll
      for (int ni = 0; ni < 4; ni++) {
        int col = cw + ni * 16 + c;
        float bias = bq[col];
#pragma unroll
        for (int j = 0; j < 4; j++) {
          int row = rowbase + mi * 16 + g * 4 + j;
          qb[row * 256 + col] = f2bf((acc[mi][ni][j] + bias) * 0.044194173824159216f);
        }
      }
  } else if (cls == 1) {
#pragma unroll
    for (int mi = 0; mi < 4; mi++)
#pragma unroll
      for (int ni = 0; ni < 4; ni++) {
        int col = cw + ni * 16 + c;
        float bias = bk[col];
#pragma unroll
        for (int j = 0; j < 4; j++) {
          int row = rowbase + mi * 16 + g * 4 + j;
          kb[row * 256 + col] = f2bf(acc[mi][ni][j] + bias);
        }
      }
  } else {
#pragma unroll
    for (int mi = 0; mi < 4; mi++)
#pragma unroll
      for (int ni = 0; ni < 4; ni++) {
        int d = cw + ni * 16 + c;
        float bias = bv[d];
        int r0 = rowbase + mi * 16 + g * 4;
        int bb = r0 >> 10, s0 = r0 & 1023;
        short4v o;
        o[0] = f2bf(acc[mi][ni][0] + bias);
        o[1] = f2bf(acc[mi][ni][1] + bias);
        o[2] = f2bf(acc[mi][ni][2] + bias);
        o[3] = f2bf(acc[mi][ni][3] + bias);
        *(short4v*)(vt + (bb * 256 + d) * 1024 + s0) = o;
      }
  }
}

// ---------------- flash attention ----------------
// grid 256 = 16 batches x 16 q-tiles(64 rows); 4 waves x 16 rows each.
// Per kt iter (64 keys): stage K[64][256], V_t[256][64] to LDS (swizzled gll),
// QK^T MFMA, online softmax (shfl reduce within 16-lane groups),
// P -> per-wave LDS tile -> A-frags, PV MFMA into O.
__global__ __launch_bounds__(256) void attn_kernel(
    const short* __restrict__ qb, const short* __restrict__ kb,
    const short* __restrict__ vt, float* __restrict__ out) {
  __shared__ __align__(16) char smem[74752];  // K 32K | V 32K | P 4x2304
  const int bid = blockIdx.x;
  const int swz = (bid & 7) * 32 + (bid >> 3);  // 2 batches per XCD chunk
  const int b = swz >> 4, qt = swz & 15;
  const int tid = threadIdx.x;
  const int w = tid >> 6, lane = tid & 63;
  const int g = lane >> 4, c = lane & 15;
  const int q0 = b * 1024 + qt * 64 + w * 16;
  const int VB = 32768, PB = 65536;
  short* sp = (short*)(smem + PB + w * 2304);

  // Q held in registers for the whole kernel (A-frags, 8 k-steps of 32 dims)
  short8 qf[8];
#pragma unroll
  for (int ks = 0; ks < 8; ks++)
    qf[ks] = *(const short8*)(qb + (q0 + c) * 256 + ks * 32 + g * 8);

  f32x4 O[16];
  const f32x4 fzero = {0.f, 0.f, 0.f, 0.f};
#pragma unroll
  for (int ni = 0; ni < 16; ni++) O[ni] = fzero;
  float m_[4] = {-1e30f, -1e30f, -1e30f, -1e30f};
  float l_[4] = {0.f, 0.f, 0.f, 0.f};

  for (int kt = 0; kt < 16; ++kt) {
    __syncthreads();
    if (w < 2) {  // K tile: 64 rows x 512B, 32 glls
#pragma unroll
      for (int i = 0; i < 16; i++) {
        int j = w * 16 + i;
        int r = j * 2 + (lane >> 5);
        int cc = lane & 31;
        const short* src = kb + (b * 1024 + kt * 64 + r) * 256 + ((cc ^ (r & 7)) * 8);
        GLL16(src, smem + j * 1024);
      }
    } else {      // V tile: 256 rows x 128B, 32 glls
#pragma unroll
      for (int i = 0; i < 16; i++) {
        int j = (w - 2) * 16 + i;
        int r = j * 8 + (lane >> 3);
        int cc = lane & 7;
        const short* src = vt + (b * 256 + r) * 1024 + kt * 64 + ((cc ^ (r & 7)) * 8);
        GLL16(src, smem + VB + j * 1024);
      }
    }
    asm volatile("s_waitcnt vmcnt(0)" ::: "memory");
    __syncthreads();

    // QK^T: S[16 rows x 64 keys] per wave
    f32x4 Sf[4];
#pragma unroll
    for (int nf = 0; nf < 4; nf++) Sf[nf] = fzero;
#pragma unroll
    for (int ks = 0; ks < 8; ks++) {
      short8 kf[4];
#pragma unroll
      for (int nf = 0; nf < 4; nf++) {
        int key = nf * 16 + c;
        kf[nf] = *(const short8*)(smem + key * 512 + (((ks * 4 + g) ^ (c & 7)) * 16));
      }
#pragma unroll
      for (int nf = 0; nf < 4; nf++)
        Sf[nf] = __builtin_amdgcn_mfma_f32_16x16x32_bf16(qf[ks], kf[nf], Sf[nf], 0, 0, 0);
    }

    // online softmax; lane holds rows 4g+j, cols c+16*nf
    float Pv[4][4], scl[4];
#pragma unroll
    for (int j = 0; j < 4; j++) {
      float tm = fmaxf(fmaxf(Sf[0][j], Sf[1][j]), fmaxf(Sf[2][j], Sf[3][j]));
      tm = fmaxf(tm, __shfl_xor(tm, 1));
      tm = fmaxf(tm, __shfl_xor(tm, 2));
      tm = fmaxf(tm, __shfl_xor(tm, 4));
      tm = fmaxf(tm, __shfl_xor(tm, 8));
      float nm = fmaxf(m_[j], tm);
      scl[j] = __expf(m_[j] - nm);
      m_[j] = nm;
      float rs = 0.f;
#pragma unroll
      for (int nf = 0; nf < 4; nf++) {
        float p = __expf(Sf[nf][j] - nm);
        Pv[nf][j] = p;
        rs += p;
      }
      rs += __shfl_xor(rs, 1);
      rs += __shfl_xor(rs, 2);
      rs += __shfl_xor(rs, 4);
      rs += __shfl_xor(rs, 8);
      l_[j] = l_[j] * scl[j] + rs;
    }
#pragma unroll
    for (int ni = 0; ni < 16; ni++) {
      O[ni][0] *= scl[0]; O[ni][1] *= scl[1];
      O[ni][2] *= scl[2]; O[ni][3] *= scl[3];
    }

    // P (bf16) -> per-wave LDS [16][72], C-layout scatter (2-way-free u16 writes)
#pragma unroll
    for (int nf = 0; nf < 4; nf++)
#pragma unroll
      for (int j = 0; j < 4; j++)
        sp[(g * 4 + j) * 72 + nf * 16 + c] = f2bf(Pv[nf][j]);

    // A-frags of P: row = c, keys = ks2*32 + 8g..+7 (same-wave, lgkmcnt only)
    short8 pf[2];
#pragma unroll
    for (int ks2 = 0; ks2 < 2; ks2++)
      pf[ks2] = *(const short8*)((char*)sp + c * 144 + ks2 * 64 + g * 16);

    // PV: O[16 rows x 256 d] += P[16x64] @ V[64x256]
#pragma unroll
    for (int ni = 0; ni < 16; ni++) {
      int d = ni * 16 + c;
#pragma unroll
      for (int ks2 = 0; ks2 < 2; ks2++) {
        short8 vf = *(const short8*)(smem + VB + d * 128 + (((ks2 * 4 + g) ^ (c & 7)) * 16));
        O[ni] = __builtin_amdgcn_mfma_f32_16x16x32_bf16(pf[ks2], vf, O[ni], 0, 0, 0);
      }
    }
  }

  // normalize + store fp32
#pragma unroll
  for (int j = 0; j < 4; j++) {
    float inv = 1.0f / l_[j];
    int row = q0 + g * 4 + j;
#pragma unroll
    for (int ni = 0; ni < 16; ni++)
      out[row * 256 + ni * 16 + c] = O[ni][j] * inv;
  }
}

extern "C" void kernel_launch(void* const* d_in, const int* in_sizes, int n_in,
                              void* d_out, int out_size, void* d_ws, size_t ws_size,
                              hipStream_t stream) {
  const float* x  = (const float*)d_in[0];
  const float* wq = (const float*)d_in[1];
  const float* bq = (const float*)d_in[2];
  const float* wk = (const float*)d_in[3];
  const float* bk = (const float*)d_in[4];
  const float* wv = (const float*)d_in[5];
  const float* bv = (const float*)d_in[6];
  float* out = (float*)d_out;
  char* ws = (char*)d_ws;
  // ws layout (bytes): xb 16,777,216 | wb 786,432 | qb 8,388,608 | kb 8,388,608 | vt 8,388,608
  short* xb = (short*)ws;
  short* wb = (short*)(ws + 16777216);
  short* qb = (short*)(ws + 17563648);
  short* kb = (short*)(ws + 25952256);
  short* vt = (short*)(ws + 34340864);

  cvt_x<<<2048, 256, 0, stream>>>(x, xb, 1048576);
  cvt_w<<<192, 256, 0, stream>>>(wq, wk, wv, wb);
  qkv_gemm<<<768, 256, 0, stream>>>(xb, wb, bq, bk, bv, qb, kb, vt);
  attn_kernel<<<256, 256, 0, stream>>>(qb, kb, vt, out);
}

// Round 2
// 167.007 us; speedup vs baseline: 1.0094x; 1.0094x over previous
//
#include <hip/hip_runtime.h>
#include <hip/hip_bf16.h>

// Problem: B=16, S=1024, IN=512, OUT=256.
// out = softmax((x@wq^T + bq)(x@wk^T + bk)^T / sqrt(512)) @ (x@wv^T + bv)
// RoPE cancels (same rotation applied to q and k) -> skipped.
// Pipeline: cvt_w (w fp32->bf16) -> qkv_gemm (A-path converts x inline,
// writes q,k scaled/biased + v transposed) -> flash attn (double-buffered).

typedef __attribute__((ext_vector_type(8))) short short8;
typedef __attribute__((ext_vector_type(4))) short short4v;
typedef __attribute__((ext_vector_type(4))) float f32x4;

#define GLL16(g, l)                                                            \
  __builtin_amdgcn_global_load_lds(                                            \
      (const __attribute__((address_space(1))) unsigned int*)(g),              \
      (__attribute__((address_space(3))) unsigned int*)(l), 16, 0, 0)

static __device__ __forceinline__ short f2bf(float f) {
  __hip_bfloat16 h = __float2bfloat16(f);
  return __builtin_bit_cast(short, h);
}

// ---------------- w fp32 -> bf16 (tiny: 1.5 MB) ----------------
__global__ void cvt_w(const float* __restrict__ wq, const float* __restrict__ wk,
                      const float* __restrict__ wv, short* __restrict__ dst) {
  int i = blockIdx.x * blockDim.x + threadIdx.x;  // 49152 * 8 = 393216 elems
  if (i >= 49152) return;
  const float* src;
  int off;
  if (i < 16384)      { src = wq; off = i; }
  else if (i < 32768) { src = wk; off = i - 16384; }
  else                { src = wv; off = i - 32768; }
  const float4* sp = reinterpret_cast<const float4*>(src) + off * 2;
  float4 a = sp[0], b = sp[1];
  short8 o;
  o[0] = f2bf(a.x); o[1] = f2bf(a.y); o[2] = f2bf(a.z); o[3] = f2bf(a.w);
  o[4] = f2bf(b.x); o[5] = f2bf(b.y); o[6] = f2bf(b.z); o[7] = f2bf(b.w);
  *(reinterpret_cast<short8*>(dst) + i) = o;
}

// ---------------- QKV GEMM ----------------
// C[16384 x 768] = x[16384 x 512](fp32, converted inline) @ wb[768 x 512]^T
// 128x128 tile, BK=64, 4 waves (2x2), wave = 64x64 = 4x4 frags of 16x16x32.
// A: reg-staged fp32->bf16 with 16B-chunk XOR swizzle ds_writes.
// B: global_load_lds with pre-swizzled source.
// Epilogue: q (scaled+bias), k (bias), v -> LDS transpose -> vt[b][d][s].
__global__ __launch_bounds__(256) void qkv_gemm(
    const float* __restrict__ x, const short* __restrict__ wb,
    const float* __restrict__ bq, const float* __restrict__ bk,
    const float* __restrict__ bv, short* __restrict__ qb,
    short* __restrict__ kb, short* __restrict__ vt) {
  __shared__ __align__(16) char smem[32768];
  const int bid = blockIdx.x;                   // 768 blocks
  const int swz = (bid & 7) * 96 + (bid >> 3);  // XCD chunking (768 % 8 == 0)
  const int mt = swz / 6, nt = swz % 6;         // 6 nt of one mt share an XCD
  const int tid = threadIdx.x;
  const int w = tid >> 6, lane = tid & 63;
  const int g = lane >> 4, c = lane & 15;
  const int wm = w >> 1, wn = w & 1;

  f32x4 acc[4][4];
  const f32x4 fzero = {0.f, 0.f, 0.f, 0.f};
#pragma unroll
  for (int mi = 0; mi < 4; mi++)
#pragma unroll
    for (int ni = 0; ni < 4; ni++) acc[mi][ni] = fzero;

  const int arow = tid >> 4;          // 0..15 (row offset within 16-row stripe)
  const int acol4 = tid & 15;         // float4 index within 64-k row
  const int achunk = acol4 >> 1, ahalf = (tid & 1) * 8;

  for (int kk = 0; kk < 8; ++kk) {
    __syncthreads();
    // B stage: 16KB via 16 glls (4 per wave)
#pragma unroll
    for (int i = 0; i < 4; i++) {
      int idx = w * 4 + i;                  // 0..15
      int r = idx * 8 + (lane >> 3);
      int cc = lane & 7;
      GLL16(wb + (nt * 128 + r) * 512 + kk * 64 + ((cc ^ (r & 7)) * 8),
            smem + 16384 + idx * 1024);
    }
    // A stage: fp32 loads (coalesced 256B rows) -> bf16 -> swizzled ds_write
    float4 xv[8];
#pragma unroll
    for (int j = 0; j < 8; j++) {
      int row = j * 16 + arow;
      xv[j] = *(const float4*)(x + (mt * 128 + row) * 512 + kk * 64 + acol4 * 4);
    }
#pragma unroll
    for (int j = 0; j < 8; j++) {
      int row = j * 16 + arow;
      short4v s4;
      s4[0] = f2bf(xv[j].x); s4[1] = f2bf(xv[j].y);
      s4[2] = f2bf(xv[j].z); s4[3] = f2bf(xv[j].w);
      *(short4v*)(smem + row * 128 + ((achunk ^ (row & 7)) * 16) + ahalf) = s4;
    }
    asm volatile("s_waitcnt vmcnt(0)" ::: "memory");
    __syncthreads();
#pragma unroll
    for (int ks = 0; ks < 2; ++ks) {
      short8 af[4], bf[4];
#pragma unroll
      for (int mi = 0; mi < 4; mi++) {
        int row = wm * 64 + mi * 16 + c;
        af[mi] = *(const short8*)(smem + row * 128 + (((ks * 4 + g) ^ (row & 7)) * 16));
      }
#pragma unroll
      for (int ni = 0; ni < 4; ni++) {
        int row = wn * 64 + ni * 16 + c;
        bf[ni] = *(const short8*)(smem + 16384 + row * 128 + (((ks * 4 + g) ^ (row & 7)) * 16));
      }
#pragma unroll
      for (int mi = 0; mi < 4; mi++)
#pragma unroll
        for (int ni = 0; ni < 4; ni++)
          acc[mi][ni] = __builtin_amdgcn_mfma_f32_16x16x32_bf16(af[mi], bf[ni], acc[mi][ni], 0, 0, 0);
    }
  }

  // epilogue — C/D layout: col = lane&15, row = (lane>>4)*4 + reg
  const int colbase = nt * 128 + wn * 64;
  const int cls = colbase >> 8;  // 0=q 1=k 2=v (uniform per block)
  const int cw = colbase & 255;
  const int rowbase = mt * 128 + wm * 64;
  if (cls == 0) {
#pragma unroll
    for (int ni = 0; ni < 4; ni++) {
      int col = cw + ni * 16 + c;
      float bias = bq[col];
#pragma unroll
      for (int mi = 0; mi < 4; mi++)
#pragma unroll
        for (int j = 0; j < 4; j++) {
          int row = rowbase + mi * 16 + g * 4 + j;
          qb[row * 256 + col] = f2bf((acc[mi][ni][j] + bias) * 0.044194173824159216f);
        }
    }
  } else if (cls == 1) {
#pragma unroll
    for (int ni = 0; ni < 4; ni++) {
      int col = cw + ni * 16 + c;
      float bias = bk[col];
#pragma unroll
      for (int mi = 0; mi < 4; mi++)
#pragma unroll
        for (int j = 0; j < 4; j++) {
          int row = rowbase + mi * 16 + g * 4 + j;
          kb[row * 256 + col] = f2bf(acc[mi][ni][j] + bias);
        }
    }
  } else {
    // v: per-wave 64(s) x 64(d) transpose through LDS, then coalesced stores
    __syncthreads();  // done with GEMM tiles; reuse smem (4 x 8KB)
    char* tb = smem + w * 8192;
#pragma unroll
    for (int ni = 0; ni < 4; ni++) {
      int dl = ni * 16 + c;
      float bias = bv[cw + dl];
#pragma unroll
      for (int mi = 0; mi < 4; mi++)
#pragma unroll
        for (int j = 0; j < 4; j++) {
          int sl = mi * 16 + g * 4 + j;
          *(short*)(tb + dl * 128 + ((sl * 2) ^ ((dl & 7) << 4))) =
              f2bf(acc[mi][ni][j] + bias);
        }
    }
    const int bb = rowbase >> 10, sb = rowbase & 1023;
#pragma unroll
    for (int i = 0; i < 8; i++) {
      int dl = i * 8 + (lane >> 3);
      int ch = lane & 7;
      short8 val = *(const short8*)(tb + dl * 128 + (((ch ^ (dl & 7)) * 16)));
      *(short8*)(vt + (bb * 256 + cw + dl) * 1024 + sb + ch * 8) = val;
    }
  }
}

// ---------------- flash attention (double-buffered K/V) ----------------
// grid 256 = 16 batches x 16 q-tiles(64 rows); 4 waves x 16 rows each.
// LDS: K0 32K | K1 32K | V0 32K | V1 32K | P 4x2304 = 140288 B.
// Per iter: vmcnt(0) -> barrier -> issue next tile's glls -> compute current.
__global__ __launch_bounds__(256) void attn_kernel(
    const short* __restrict__ qb, const short* __restrict__ kb,
    const short* __restrict__ vt, float* __restrict__ out) {
  __shared__ __align__(16) char smem[140288];
  const int bid = blockIdx.x;
  const int swz = (bid & 7) * 32 + (bid >> 3);  // 2 batches per XCD chunk
  const int b = swz >> 4, qt = swz & 15;
  const int tid = threadIdx.x;
  const int w = tid >> 6, lane = tid & 63;
  const int g = lane >> 4, c = lane & 15;
  const int q0 = b * 1024 + qt * 64 + w * 16;
  const int VB = 65536, PB = 131072;
  short* sp = (short*)(smem + PB + w * 2304);

  // Q held in registers (A-frags, 8 k-steps of 32 dims)
  short8 qf[8];
#pragma unroll
  for (int ks = 0; ks < 8; ks++)
    qf[ks] = *(const short8*)(qb + (q0 + c) * 256 + ks * 32 + g * 8);

  f32x4 O[16];
  const f32x4 fzero = {0.f, 0.f, 0.f, 0.f};
#pragma unroll
  for (int ni = 0; ni < 16; ni++) O[ni] = fzero;
  float m_[4] = {-1e30f, -1e30f, -1e30f, -1e30f};
  float l_[4] = {0.f, 0.f, 0.f, 0.f};

  // staging lambda: 16 glls per wave into buffer bsel
  auto stage = [&](int kt, int bsel) {
    if (w < 2) {  // K tile: 64 rows x 512B
#pragma unroll
      for (int i = 0; i < 16; i++) {
        int j = w * 16 + i;
        int r = j * 2 + (lane >> 5);
        int cc = lane & 31;
        GLL16(kb + (b * 1024 + kt * 64 + r) * 256 + ((cc ^ (r & 7)) * 8),
              smem + bsel * 32768 + j * 1024);
      }
    } else {      // V tile: 256 rows x 128B
#pragma unroll
      for (int i = 0; i < 16; i++) {
        int j = (w - 2) * 16 + i;
        int r = j * 8 + (lane >> 3);
        int cc = lane & 7;
        GLL16(vt + (b * 256 + r) * 1024 + kt * 64 + ((cc ^ (r & 7)) * 8),
              smem + VB + bsel * 32768 + j * 1024);
      }
    }
  };

  stage(0, 0);
  for (int kt = 0; kt < 16; ++kt) {
    const int cur = kt & 1;
    const char* kbase = smem + cur * 32768;
    const char* vbase = smem + VB + cur * 32768;
    asm volatile("s_waitcnt vmcnt(0)" ::: "memory");
    __syncthreads();
    if (kt < 15) stage(kt + 1, cur ^ 1);  // loads fly under compute

    // QK^T: S[16 rows x 64 keys] per wave
    f32x4 Sf[4];
#pragma unroll
    for (int nf = 0; nf < 4; nf++) Sf[nf] = fzero;
#pragma unroll
    for (int ks = 0; ks < 8; ks++) {
      short8 kf[4];
#pragma unroll
      for (int nf = 0; nf < 4; nf++) {
        int key = nf * 16 + c;
        kf[nf] = *(const short8*)(kbase + key * 512 + (((ks * 4 + g) ^ (c & 7)) * 16));
      }
#pragma unroll
      for (int nf = 0; nf < 4; nf++)
        Sf[nf] = __builtin_amdgcn_mfma_f32_16x16x32_bf16(qf[ks], kf[nf], Sf[nf], 0, 0, 0);
    }

    // online softmax; lane holds rows 4g+j, cols c+16*nf
    float Pv[4][4], scl[4];
#pragma unroll
    for (int j = 0; j < 4; j++) {
      float tm = fmaxf(fmaxf(Sf[0][j], Sf[1][j]), fmaxf(Sf[2][j], Sf[3][j]));
      tm = fmaxf(tm, __shfl_xor(tm, 1));
      tm = fmaxf(tm, __shfl_xor(tm, 2));
      tm = fmaxf(tm, __shfl_xor(tm, 4));
      tm = fmaxf(tm, __shfl_xor(tm, 8));
      float nm = fmaxf(m_[j], tm);
      scl[j] = __expf(m_[j] - nm);
      m_[j] = nm;
      float rs = 0.f;
#pragma unroll
      for (int nf = 0; nf < 4; nf++) {
        float p = __expf(Sf[nf][j] - nm);
        Pv[nf][j] = p;
        rs += p;
      }
      rs += __shfl_xor(rs, 1);
      rs += __shfl_xor(rs, 2);
      rs += __shfl_xor(rs, 4);
      rs += __shfl_xor(rs, 8);
      l_[j] = l_[j] * scl[j] + rs;
    }
#pragma unroll
    for (int ni = 0; ni < 16; ni++) {
      O[ni][0] *= scl[0]; O[ni][1] *= scl[1];
      O[ni][2] *= scl[2]; O[ni][3] *= scl[3];
    }

    // P (bf16) -> per-wave LDS [16][72] -> A-frags
#pragma unroll
    for (int nf = 0; nf < 4; nf++)
#pragma unroll
      for (int j = 0; j < 4; j++)
        sp[(g * 4 + j) * 72 + nf * 16 + c] = f2bf(Pv[nf][j]);

    short8 pf[2];
#pragma unroll
    for (int ks2 = 0; ks2 < 2; ks2++)
      pf[ks2] = *(const short8*)((char*)sp + c * 144 + ks2 * 64 + g * 16);

    // PV: O[16 rows x 256 d] += P[16x64] @ V[64x256]
#pragma unroll
    for (int ni = 0; ni < 16; ni++) {
      int d = ni * 16 + c;
#pragma unroll
      for (int ks2 = 0; ks2 < 2; ks2++) {
        short8 vf = *(const short8*)(vbase + d * 128 + (((ks2 * 4 + g) ^ (c & 7)) * 16));
        O[ni] = __builtin_amdgcn_mfma_f32_16x16x32_bf16(pf[ks2], vf, O[ni], 0, 0, 0);
      }
    }
  }

  // normalize + store fp32
#pragma unroll
  for (int j = 0; j < 4; j++) {
    float inv = 1.0f / l_[j];
    int row = q0 + g * 4 + j;
#pragma unroll
    for (int ni = 0; ni < 16; ni++)
      out[row * 256 + ni * 16 + c] = O[ni][j] * inv;
  }
}

extern "C" void kernel_launch(void* const* d_in, const int* in_sizes, int n_in,
                              void* d_out, int out_size, void* d_ws, size_t ws_size,
                              hipStream_t stream) {
  const float* x  = (const float*)d_in[0];
  const float* wq = (const float*)d_in[1];
  const float* bq = (const float*)d_in[2];
  const float* wk = (const float*)d_in[3];
  const float* bk = (const float*)d_in[4];
  const float* wv = (const float*)d_in[5];
  const float* bv = (const float*)d_in[6];
  float* out = (float*)d_out;
  char* ws = (char*)d_ws;
  // ws layout (bytes): wb 786,432 | qb 8,388,608 | kb 8,388,608 | vt 8,388,608
  short* wb = (short*)ws;
  short* qb = (short*)(ws + 786432);
  short* kb = (short*)(ws + 9175040);
  short* vt = (short*)(ws + 17563648);

  cvt_w<<<192, 256, 0, stream>>>(wq, wk, wv, wb);
  qkv_gemm<<<768, 256, 0, stream>>>(x, wb, bq, bk, bv, qb, kb, vt);
  attn_kernel<<<256, 256, 0, stream>>>(qb, kb, vt, out);
}

// Round 4
// 156.310 us; speedup vs baseline: 1.0785x; 1.0684x over previous
//
#include <hip/hip_runtime.h>
#include <hip/hip_bf16.h>

// Problem: B=16, S=1024, IN=512, OUT=256.
// out = softmax((x@wq^T + bq)(x@wk^T + bk)^T / sqrt(512)) @ (x@wv^T + bv)
// RoPE cancels (same rotation applied to q and k) -> skipped.
// Two kernels: qkv_gemm (reads fp32 x,w directly; converts inline; writes
// q scaled+biased, k biased, v transposed) -> attn (in-block split-K flash,
// 8 waves: waves 0-3 keys 0..511, waves 4-7 keys 512..1023, LDS merge).

typedef __attribute__((ext_vector_type(8))) short short8;
typedef __attribute__((ext_vector_type(4))) short short4v;
typedef __attribute__((ext_vector_type(4))) float f32x4;

#define GLL16(g, l)                                                            \
  __builtin_amdgcn_global_load_lds(                                            \
      (const __attribute__((address_space(1))) unsigned int*)(g),              \
      (__attribute__((address_space(3))) unsigned int*)(l), 16, 0, 0)

static __device__ __forceinline__ short f2bf(float f) {
  __hip_bfloat16 h = __float2bfloat16(f);
  return __builtin_bit_cast(short, h);
}

// ---------------- QKV GEMM ----------------
// C[16384 x 768] = x[16384 x 512] @ w[768 x 512]^T, fp32 in, bf16 MFMA.
// 128x128 tile, BK=64, 4 waves (2x2), wave = 64x64 = 4x4 frags of 16x16x32.
// Both A and B reg-staged: float4 load -> cvt bf16 -> 16B-chunk-XOR ds_write.
__global__ __launch_bounds__(256) void qkv_gemm(
    const float* __restrict__ x, const float* __restrict__ wq,
    const float* __restrict__ wk, const float* __restrict__ wv,
    const float* __restrict__ bq, const float* __restrict__ bk,
    const float* __restrict__ bv, short* __restrict__ qb,
    short* __restrict__ kb, short* __restrict__ vt) {
  __shared__ __align__(16) char smem[32768];
  const int bid = blockIdx.x;                   // 768 blocks
  const int swz = (bid & 7) * 96 + (bid >> 3);  // XCD chunking (768 % 8 == 0)
  const int mt = swz / 6, nt = swz % 6;         // 6 nt of one mt share an XCD
  const int tid = threadIdx.x;
  const int w = tid >> 6, lane = tid & 63;
  const int g = lane >> 4, c = lane & 15;
  const int wm = w >> 1, wn = w & 1;

  const float* wsel = (nt < 2) ? wq : (nt < 4) ? wk : wv;
  const int wro = (nt & 1) * 128;  // row offset within the selected w matrix

  f32x4 acc[4][4];
  const f32x4 fzero = {0.f, 0.f, 0.f, 0.f};
#pragma unroll
  for (int mi = 0; mi < 4; mi++)
#pragma unroll
    for (int ni = 0; ni < 4; ni++) acc[mi][ni] = fzero;

  const int arow = tid >> 4;   // 0..15
  const int acol4 = tid & 15;  // float4 index within 64-wide k slice
  const int achunk = acol4 >> 1, ahalf = (tid & 1) * 8;

  for (int kk = 0; kk < 8; ++kk) {
    __syncthreads();
    float4 xv[8], wv8[8];
#pragma unroll
    for (int j = 0; j < 8; j++) {
      int row = j * 16 + arow;
      xv[j] = *(const float4*)(x + (mt * 128 + row) * 512 + kk * 64 + acol4 * 4);
    }
#pragma unroll
    for (int j = 0; j < 8; j++) {
      int row = j * 16 + arow;
      wv8[j] = *(const float4*)(wsel + (wro + row) * 512 + kk * 64 + acol4 * 4);
    }
#pragma unroll
    for (int j = 0; j < 8; j++) {
      int row = j * 16 + arow;
      short4v s4;
      s4[0] = f2bf(xv[j].x); s4[1] = f2bf(xv[j].y);
      s4[2] = f2bf(xv[j].z); s4[3] = f2bf(xv[j].w);
      *(short4v*)(smem + row * 128 + ((achunk ^ (row & 7)) * 16) + ahalf) = s4;
      short4v t4;
      t4[0] = f2bf(wv8[j].x); t4[1] = f2bf(wv8[j].y);
      t4[2] = f2bf(wv8[j].z); t4[3] = f2bf(wv8[j].w);
      *(short4v*)(smem + 16384 + row * 128 + ((achunk ^ (row & 7)) * 16) + ahalf) = t4;
    }
    __syncthreads();
#pragma unroll
    for (int ks = 0; ks < 2; ++ks) {
      short8 af[4], bf[4];
#pragma unroll
      for (int mi = 0; mi < 4; mi++) {
        int row = wm * 64 + mi * 16 + c;
        af[mi] = *(const short8*)(smem + row * 128 + (((ks * 4 + g) ^ (row & 7)) * 16));
      }
#pragma unroll
      for (int ni = 0; ni < 4; ni++) {
        int row = wn * 64 + ni * 16 + c;
        bf[ni] = *(const short8*)(smem + 16384 + row * 128 + (((ks * 4 + g) ^ (row & 7)) * 16));
      }
#pragma unroll
      for (int mi = 0; mi < 4; mi++)
#pragma unroll
        for (int ni = 0; ni < 4; ni++)
          acc[mi][ni] = __builtin_amdgcn_mfma_f32_16x16x32_bf16(af[mi], bf[ni], acc[mi][ni], 0, 0, 0);
    }
  }

  // epilogue — C/D layout: col = lane&15, row = (lane>>4)*4 + reg
  const int cls = nt >> 1;                   // 0=q 1=k 2=v (block-uniform)
  const int cw = (nt & 1) * 128 + wn * 64;   // col base within the 256-wide matrix
  const int rowbase = mt * 128 + wm * 64;
  if (cls == 0) {
#pragma unroll
    for (int ni = 0; ni < 4; ni++) {
      int col = cw + ni * 16 + c;
      float bias = bq[col];
#pragma unroll
      for (int mi = 0; mi < 4; mi++)
#pragma unroll
        for (int j = 0; j < 4; j++) {
          int row = rowbase + mi * 16 + g * 4 + j;
          qb[row * 256 + col] = f2bf((acc[mi][ni][j] + bias) * 0.044194173824159216f);
        }
    }
  } else if (cls == 1) {
#pragma unroll
    for (int ni = 0; ni < 4; ni++) {
      int col = cw + ni * 16 + c;
      float bias = bk[col];
#pragma unroll
      for (int mi = 0; mi < 4; mi++)
#pragma unroll
        for (int j = 0; j < 4; j++) {
          int row = rowbase + mi * 16 + g * 4 + j;
          kb[row * 256 + col] = f2bf(acc[mi][ni][j] + bias);
        }
    }
  } else {
    // v: per-wave 64(s) x 64(d) transpose through LDS, then coalesced stores
    __syncthreads();  // GEMM tiles done; reuse smem (4 x 8KB)
    char* tb = smem + w * 8192;
#pragma unroll
    for (int ni = 0; ni < 4; ni++) {
      int dl = ni * 16 + c;
      float bias = bv[cw + dl];
#pragma unroll
      for (int mi = 0; mi < 4; mi++)
#pragma unroll
        for (int j = 0; j < 4; j++) {
          int sl = mi * 16 + g * 4 + j;
          *(short*)(tb + dl * 128 + ((sl * 2) ^ ((dl & 7) << 4))) =
              f2bf(acc[mi][ni][j] + bias);
        }
    }
    const int bb = rowbase >> 10, sb = rowbase & 1023;
#pragma unroll
    for (int i = 0; i < 8; i++) {
      int dl = i * 8 + (lane >> 3);
      int ch = lane & 7;
      short8 val = *(const short8*)(tb + dl * 128 + ((ch ^ (dl & 7)) * 16));
      *(short8*)(vt + (bb * 256 + cw + dl) * 1024 + sb + ch * 8) = val;
    }
  }
}

// ---------------- flash attention, in-block split-K ----------------
// grid 256 = 16 batches x 16 q-tiles(64 rows); 512 threads = 8 waves.
// Waves 0-3 (grp 0): keys 0..511; waves 4-7 (grp 1): keys 512..1023.
// Same 64 q-rows both groups (wave lw owns rows lw*16..+15). 8 kt iters.
// LDS: K[2][32K] | V[2][32K] | P 8x2304 = 149504 B. End: merge via LDS.
// NOTE: m_/l_ are distinct per g (rows g*4+j) -> merge buffer indexed
// [lw][g*4+j]; the 16 c-lanes of one (g,j) write identical values (benign).
__global__ __launch_bounds__(512) void attn_kernel(
    const short* __restrict__ qb, const short* __restrict__ kb,
    const short* __restrict__ vt, float* __restrict__ out) {
  __shared__ __align__(16) char smem[149504];
  const int bid = blockIdx.x;
  const int swz = (bid & 7) * 32 + (bid >> 3);  // 2 batches per XCD chunk
  const int b = swz >> 4, qt = swz & 15;
  const int tid = threadIdx.x;
  const int w = tid >> 6, lane = tid & 63;
  const int grp = w >> 2, lw = w & 3;
  const int g = lane >> 4, c = lane & 15;
  const int q0 = b * 1024 + qt * 64 + lw * 16;
  char* kbase = smem + grp * 32768;
  char* vbase = smem + 65536 + grp * 32768;
  short* sp = (short*)(smem + 131072 + w * 2304);

  // Q in registers (A-frags, 8 k-steps of 32 dims) — same rows both groups
  short8 qf[8];
#pragma unroll
  for (int ks = 0; ks < 8; ks++)
    qf[ks] = *(const short8*)(qb + (q0 + c) * 256 + ks * 32 + g * 8);

  f32x4 O[16];
  const f32x4 fzero = {0.f, 0.f, 0.f, 0.f};
#pragma unroll
  for (int ni = 0; ni < 16; ni++) O[ni] = fzero;
  float m_[4] = {-1e30f, -1e30f, -1e30f, -1e30f};
  float l_[4] = {0.f, 0.f, 0.f, 0.f};

  const int krow0 = b * 1024 + grp * 512;

  for (int kt = 0; kt < 8; ++kt) {
    __syncthreads();
    if (lw < 2) {  // K tile: 64 rows x 512B, 32 glls over 2 waves
#pragma unroll
      for (int i = 0; i < 16; i++) {
        int j = lw * 16 + i;
        int r = j * 2 + (lane >> 5);
        int cc = lane & 31;
        GLL16(kb + (krow0 + kt * 64 + r) * 256 + ((cc ^ (r & 7)) * 8),
              kbase + j * 1024);
      }
    } else {       // V tile: 256 rows x 128B, 32 glls over 2 waves
#pragma unroll
      for (int i = 0; i < 16; i++) {
        int j = (lw - 2) * 16 + i;
        int r = j * 8 + (lane >> 3);
        int cc = lane & 7;
        GLL16(vt + (b * 256 + r) * 1024 + grp * 512 + kt * 64 + ((cc ^ (r & 7)) * 8),
              vbase + j * 1024);
      }
    }
    asm volatile("s_waitcnt vmcnt(0)" ::: "memory");
    __syncthreads();

    // QK^T: S[16 rows x 64 keys] per wave
    f32x4 Sf[4];
#pragma unroll
    for (int nf = 0; nf < 4; nf++) Sf[nf] = fzero;
#pragma unroll
    for (int ks = 0; ks < 8; ks++) {
      short8 kf[4];
#pragma unroll
      for (int nf = 0; nf < 4; nf++) {
        int key = nf * 16 + c;
        kf[nf] = *(const short8*)(kbase + key * 512 + (((ks * 4 + g) ^ (c & 7)) * 16));
      }
#pragma unroll
      for (int nf = 0; nf < 4; nf++)
        Sf[nf] = __builtin_amdgcn_mfma_f32_16x16x32_bf16(qf[ks], kf[nf], Sf[nf], 0, 0, 0);
    }

    // online softmax; lane holds rows 4g+j, cols c+16*nf
    float Pv[4][4], scl[4];
#pragma unroll
    for (int j = 0; j < 4; j++) {
      float tm = fmaxf(fmaxf(Sf[0][j], Sf[1][j]), fmaxf(Sf[2][j], Sf[3][j]));
      tm = fmaxf(tm, __shfl_xor(tm, 1));
      tm = fmaxf(tm, __shfl_xor(tm, 2));
      tm = fmaxf(tm, __shfl_xor(tm, 4));
      tm = fmaxf(tm, __shfl_xor(tm, 8));
      float nm = fmaxf(m_[j], tm);
      scl[j] = __expf(m_[j] - nm);
      m_[j] = nm;
      float rs = 0.f;
#pragma unroll
      for (int nf = 0; nf < 4; nf++) {
        float p = __expf(Sf[nf][j] - nm);
        Pv[nf][j] = p;
        rs += p;
      }
      rs += __shfl_xor(rs, 1);
      rs += __shfl_xor(rs, 2);
      rs += __shfl_xor(rs, 4);
      rs += __shfl_xor(rs, 8);
      l_[j] = l_[j] * scl[j] + rs;
    }
#pragma unroll
    for (int ni = 0; ni < 16; ni++) {
      O[ni][0] *= scl[0]; O[ni][1] *= scl[1];
      O[ni][2] *= scl[2]; O[ni][3] *= scl[3];
    }

    // P (bf16) -> per-wave LDS [16][72] -> A-frags (same wave, lgkm only)
#pragma unroll
    for (int nf = 0; nf < 4; nf++)
#pragma unroll
      for (int j = 0; j < 4; j++)
        sp[(g * 4 + j) * 72 + nf * 16 + c] = f2bf(Pv[nf][j]);

    short8 pf[2];
#pragma unroll
    for (int ks2 = 0; ks2 < 2; ks2++)
      pf[ks2] = *(const short8*)((char*)sp + c * 144 + ks2 * 64 + g * 16);

    // PV: O[16 rows x 256 d] += P[16x64] @ V[64x256]
#pragma unroll
    for (int ni = 0; ni < 16; ni++) {
      int d = ni * 16 + c;
#pragma unroll
      for (int ks2 = 0; ks2 < 2; ks2++) {
        short8 vf = *(const short8*)(vbase + d * 128 + (((ks2 * 4 + g) ^ (c & 7)) * 16));
        O[ni] = __builtin_amdgcn_mfma_f32_16x16x32_bf16(pf[ks2], vf, O[ni], 0, 0, 0);
      }
    }
  }

  // ---- merge the two key-halves through LDS ----
  __syncthreads();  // all waves done reading K/V tiles
  if (grp == 1) {
    // O: [256 d][16 rows + 4 pad] f32 per wave (20480 B); f32x4 spans rows j
    char* ob = smem + lw * 20480;
#pragma unroll
    for (int ni = 0; ni < 16; ni++)
      *(f32x4*)(ob + (ni * 16 + c) * 80 + g * 16) = O[ni];
    // m/l: per-row slot [lw][g*4+j]; all 16 c-lanes write identical values
    float2* mlb = (float2*)(smem + 131072);
#pragma unroll
    for (int j = 0; j < 4; j++) {
      float2 ml; ml.x = m_[j]; ml.y = l_[j];
      mlb[lw * 16 + g * 4 + j] = ml;
    }
  }
  __syncthreads();
  if (grp == 0) {
    char* ob = smem + lw * 20480;
    const float2* mlb = (const float2*)(smem + 131072);
    float a1[4], a2[4], inv[4];
#pragma unroll
    for (int j = 0; j < 4; j++) {
      float2 ml2 = mlb[lw * 16 + g * 4 + j];
      float mm = fmaxf(m_[j], ml2.x);
      a1[j] = __expf(m_[j] - mm);
      a2[j] = __expf(ml2.x - mm);
      float l = a1[j] * l_[j] + a2[j] * ml2.y;
      inv[j] = 1.0f / l;
    }
#pragma unroll
    for (int ni = 0; ni < 16; ni++) {
      f32x4 o2 = *(const f32x4*)(ob + (ni * 16 + c) * 80 + g * 16);
#pragma unroll
      for (int j = 0; j < 4; j++) {
        int row = q0 + g * 4 + j;
        out[row * 256 + ni * 16 + c] = (a1[j] * O[ni][j] + a2[j] * o2[j]) * inv[j];
      }
    }
  }
}

extern "C" void kernel_launch(void* const* d_in, const int* in_sizes, int n_in,
                              void* d_out, int out_size, void* d_ws, size_t ws_size,
                              hipStream_t stream) {
  const float* x  = (const float*)d_in[0];
  const float* wq = (const float*)d_in[1];
  const float* bq = (const float*)d_in[2];
  const float* wk = (const float*)d_in[3];
  const float* bk = (const float*)d_in[4];
  const float* wv = (const float*)d_in[5];
  const float* bv = (const float*)d_in[6];
  float* out = (float*)d_out;
  char* ws = (char*)d_ws;
  // ws layout (bytes): qb 8,388,608 | kb 8,388,608 | vt 8,388,608
  short* qb = (short*)ws;
  short* kb = (short*)(ws + 8388608);
  short* vt = (short*)(ws + 16777216);

  qkv_gemm<<<768, 256, 0, stream>>>(x, wq, wk, wv, bq, bk, bv, qb, kb, vt);
  attn_kernel<<<256, 512, 0, stream>>>(qb, kb, vt, out);
}